// Round 7
// baseline (93.899 us; speedup 1.0000x reference)
//
#include <hip/hip_runtime.h>
#include <hip/hip_bf16.h>
#include <stdint.h>

#define B_ 8
#define N_ 2048
#define F_ 128
#define D_ 128

typedef short bf16x8 __attribute__((ext_vector_type(8)));
typedef float f32x4 __attribute__((ext_vector_type(4)));

__device__ __forceinline__ unsigned short f2bf(float f) {
    unsigned u = __float_as_uint(f);
    u += 0x7fffu + ((u >> 16) & 1u);
    return (unsigned short)(u >> 16);
}

// One cooperative kernel, 256 blocks (1/CU), 512 threads.
// Block bid: batch b = bid&7 (== XCD), slab nt = bid>>3, rows R0 = nt*64.
// Phase F: gt[b][d][R0..R0+63] = (X@W + bias)^T  (bf16, unscaled)
// Phase D: rs[b][R0..R0+63] = rsqrt(rowsum(adj))  -> release flag[b*32+nt]
// Phase G: acquire batch's 32 flags, then out = relu(rs[n] * (adj*rs[m]) @ gt^T)
//          (R6-proven GEMM body: BM=64 BN=128 BK=128, counted vmcnt(8) pipeline)
__global__ __launch_bounds__(512, 1) void k_fused(const float* __restrict__ adj,
                                                  const float* __restrict__ x,
                                                  const float* __restrict__ W,
                                                  const float* __restrict__ bias,
                                                  float* __restrict__ rs,
                                                  unsigned short* __restrict__ gt,
                                                  unsigned int* __restrict__ flags,
                                                  float* __restrict__ out) {
    __shared__ __align__(16) unsigned char lds[104 * 1024];
    // feat overlay: sX = lds[0..16K), sW = lds[16K..48K)
    // gemm overlay: sA[2] = lds[0..32K), sB[2] = lds[32K..96K), sRS = lds[96K..104K)
    unsigned char* sX = lds;
    unsigned char* sW = lds + 16 * 1024;
    float* sRS = (float*)(lds + 96 * 1024);

    const int t = threadIdx.x;
    const int bid = blockIdx.x;
    const int b = bid & 7;
    const int nt = bid >> 3;
    const int R0 = nt * 64;

    const float* adjB = adj + (size_t)b * N_ * N_ + (size_t)R0 * N_;
    const unsigned short* gtB = gt + (size_t)b * D_ * N_;
    const float* rsB = rs + (size_t)b * N_;

    const int w = t >> 6, l = t & 63, lr = l & 15, lh = l >> 4;

    // =================== Phase F: feat (own slab) ===================
    {
        // stage sW = W^T [d][f] bf16 swz (coalesced W read, scattered b16 writes)
#pragma unroll
        for (int i = 0; i < 8; ++i) {
            int c = i * 512 + t;               // 4096 chunks of 4 floats
            int f = c >> 5, d0 = (c & 31) * 4;
            float4 v = *(const float4*)(W + (size_t)f * D_ + d0);
            float vv[4] = {v.x, v.y, v.z, v.w};
#pragma unroll
            for (int e = 0; e < 4; ++e) {
                int dd = d0 + e;
                unsigned byte = (unsigned)(dd * 256 + f * 2);
                byte ^= ((byte >> 8) & 15u) << 4;
                *(unsigned short*)(sW + byte) = f2bf(vv[e]);
            }
        }
        // stage sX rows R0..R0+63 of x[b]
#pragma unroll
        for (int j = 0; j < 2; ++j) {
            int c = j * 512 + t;               // 1024 chunks of 16B
            int row = c >> 4, sub = c & 15;
            const float4* src = (const float4*)(x + (size_t)(b * N_ + R0 + row) * F_ + sub * 8);
            float4 v0 = src[0], v1 = src[1];
            union { bf16x8 v; unsigned short u[8]; } pk;
            pk.u[0] = f2bf(v0.x); pk.u[1] = f2bf(v0.y); pk.u[2] = f2bf(v0.z); pk.u[3] = f2bf(v0.w);
            pk.u[4] = f2bf(v1.x); pk.u[5] = f2bf(v1.y); pk.u[6] = f2bf(v1.z); pk.u[7] = f2bf(v1.w);
            unsigned byte = (unsigned)(row * 256 + sub * 16);
            byte ^= ((byte >> 8) & 7u) << 4;
            *(bf16x8*)(sX + byte) = pk.v;
        }
        __syncthreads();

        const int rw = w & 3, ch = w >> 2;     // wave: rows rw*16, col-half ch*64
        f32x4 acc4[4];
#pragma unroll
        for (int j = 0; j < 4; ++j) acc4[j] = (f32x4){0.f, 0.f, 0.f, 0.f};
#pragma unroll
        for (int ks = 0; ks < 4; ++ks) {
            unsigned abyte = (unsigned)((rw * 16 + lr) * 256 + lh * 16 + ks * 64);
            abyte ^= ((abyte >> 8) & 7u) << 4;
            bf16x8 a = *(const bf16x8*)(sX + abyte);
#pragma unroll
            for (int j = 0; j < 4; ++j) {
                int d = ch * 64 + j * 16 + lr;
                unsigned bbyte = (unsigned)(d * 256 + lh * 16 + ks * 64);
                bbyte ^= ((bbyte >> 8) & 15u) << 4;
                bf16x8 bb = *(const bf16x8*)(sW + bbyte);
                acc4[j] = __builtin_amdgcn_mfma_f32_16x16x32_bf16(a, bb, acc4[j], 0, 0, 0);
            }
        }
        const int m0 = R0 + rw * 16 + lh * 4;
#pragma unroll
        for (int j = 0; j < 4; ++j) {
            int d = ch * 64 + j * 16 + lr;
            float bv = bias[d];
#pragma unroll
            for (int r = 0; r < 4; ++r)
                gt[((size_t)b * D_ + d) * N_ + m0 + r] = f2bf(acc4[j][r] + bv);
        }
    }

    // =================== Phase D: rowsums (own slab) ===================
    {
#pragma unroll 2
        for (int rr = 0; rr < 8; ++rr) {
            int row = R0 + w * 8 + rr;
            const float4* p = (const float4*)(adj + (size_t)(b * N_ + row) * N_);
            float s = 0.f;
#pragma unroll
            for (int j = 0; j < 8; ++j) {
                float4 v = p[j * 64 + l];
                s += (v.x + v.y) + (v.z + v.w);
            }
#pragma unroll
            for (int m = 1; m < 64; m <<= 1) s += __shfl_xor(s, m, 64);
            if (l == 0) rs[b * N_ + row] = (s > 0.f) ? (1.0f / sqrtf(s)) : 0.f;
        }
    }
    __syncthreads();
    if (t == 0)
        __hip_atomic_store(&flags[b * 32 + nt], 1u, __ATOMIC_RELEASE, __HIP_MEMORY_SCOPE_AGENT);

    // acquire all 32 slabs of this batch (siblings finish ~simultaneously)
    if (t < 32) {
        while (__hip_atomic_load(&flags[b * 32 + t], __ATOMIC_ACQUIRE, __HIP_MEMORY_SCOPE_AGENT) == 0u)
            __builtin_amdgcn_s_sleep(2);
    }
    __syncthreads();

    // =================== Phase G: GEMM (R6-proven body) ===================
    unsigned char* sA0 = lds;                 // [2][16 KB]
    unsigned char* sB0 = lds + 32 * 1024;     // [2][32 KB]
    const int wr = w >> 2, wc = w & 3;        // wave tile rows wr*32, cols wc*32

    // B geometry: 4 chunks/thread, linear LDS dest + inverse-swizzled global src
    const unsigned short* bSrc[4];
    unsigned bL[4];
#pragma unroll
    for (int i = 0; i < 4; ++i) {
        unsigned c = (unsigned)(i * 512 + t);
        unsigned L = c * 16u;
        unsigned lg = L ^ (((L >> 8) & 7u) << 4);
        bL[i] = L;
        bSrc[i] = gtB + (size_t)(lg >> 8) * N_ + ((lg & 255u) >> 1);
    }
    auto issueB = [&](int buf, int k0) {
        unsigned char* pB = sB0 + buf * 32 * 1024;
#pragma unroll
        for (int i = 0; i < 4; ++i) {
            __builtin_amdgcn_global_load_lds(
                (const __attribute__((address_space(1))) void*)(bSrc[i] + k0),
                (__attribute__((address_space(3))) void*)(pB + bL[i]), 16, 0, 0);
        }
    };

    // A geometry: thread owns 16 consecutive m at row t>>3
    const float* aSrc = adjB + (size_t)(t >> 3) * N_ + (t & 7) * 16;
    const unsigned aRow = (unsigned)(t >> 3);
    const unsigned aBase = aRow * 256u + (unsigned)((t & 7) * 32);
    const unsigned aSwz = (aRow & 7u) << 4;
    const int rsIdx0 = (t & 7) * 4;

    f32x4 acc[2][2];
#pragma unroll
    for (int i = 0; i < 2; ++i)
#pragma unroll
        for (int jn = 0; jn < 2; ++jn) acc[i][jn] = (f32x4){0.f, 0.f, 0.f, 0.f};

    // prologue: sRS DMA + stage(0)
    __builtin_amdgcn_global_load_lds(
        (const __attribute__((address_space(1))) void*)((const unsigned char*)rsB + t * 16),
        (__attribute__((address_space(3))) void*)((unsigned char*)sRS + t * 16), 16, 0, 0);
    issueB(0, 0);
    f32x4 aA[4];
#pragma unroll
    for (int j = 0; j < 4; ++j) aA[j] = *(const f32x4*)(aSrc + j * 4);
    asm volatile("s_waitcnt vmcnt(8)" ::: "memory");   // sRS landed
    __builtin_amdgcn_s_barrier();

    const int NITER = N_ / 128;  // 16
    for (int it = 0; it < NITER; ++it) {
        const int cur = it & 1;
        f32x4 nA[4];
#pragma unroll
        for (int j = 0; j < 4; ++j) nA[j] = aA[j];
        if (it + 1 < NITER) {
            issueB(cur ^ 1, (it + 1) * 128);
            const float* s = aSrc + (it + 1) * 128;
#pragma unroll
            for (int j = 0; j < 4; ++j) nA[j] = *(const f32x4*)(s + j * 4);
            asm volatile("s_waitcnt vmcnt(8)" ::: "memory");
        } else {
            asm volatile("s_waitcnt vmcnt(0)" ::: "memory");
        }
        __builtin_amdgcn_sched_barrier(0);

        // write-late: scale A(it) by rs[m], cvt, store to sA[cur]
        {
            const f32x4* rsV = (const f32x4*)sRS + (it * 32 + rsIdx0);
            unsigned u[8];
#pragma unroll
            for (int j = 0; j < 4; ++j) {
                f32x4 xj = aA[j] * rsV[j];
                asm("v_cvt_pk_bf16_f32 %0, %1, %2" : "=v"(u[2 * j]) : "v"(xj[0]), "v"(xj[1]));
                asm("v_cvt_pk_bf16_f32 %0, %1, %2" : "=v"(u[2 * j + 1]) : "v"(xj[2]), "v"(xj[3]));
            }
            union { unsigned u[4]; bf16x8 v; } p0, p1;
            p0.u[0] = u[0]; p0.u[1] = u[1]; p0.u[2] = u[2]; p0.u[3] = u[3];
            p1.u[0] = u[4]; p1.u[1] = u[5]; p1.u[2] = u[6]; p1.u[3] = u[7];
            unsigned char* pA = sA0 + cur * 16 * 1024;
            *(bf16x8*)(pA + (aBase ^ aSwz)) = p0.v;
            *(bf16x8*)(pA + ((aBase + 16) ^ aSwz)) = p1.v;
        }
        asm volatile("s_waitcnt lgkmcnt(0)" ::: "memory");
        __builtin_amdgcn_sched_barrier(0);
        __builtin_amdgcn_s_barrier();

        // compute(it): 16 MFMA/wave
        const unsigned char* pA = sA0 + cur * 16 * 1024;
        const unsigned char* pB = sB0 + cur * 32 * 1024;
#pragma unroll
        for (int kk = 0; kk < 4; ++kk) {
            bf16x8 a[2], bb[2];
#pragma unroll
            for (int i = 0; i < 2; ++i) {
                unsigned row = (unsigned)(wr * 32 + i * 16 + lr);
                unsigned byte = row * 256 + (unsigned)(kk * 64 + lh * 16);
                byte ^= (row & 7u) << 4;
                a[i] = *(const bf16x8*)(pA + byte);
            }
#pragma unroll
            for (int jn = 0; jn < 2; ++jn) {
                unsigned d = (unsigned)(wc * 32 + jn * 16 + lr);
                unsigned byte = d * 256 + (unsigned)(kk * 64 + lh * 16);
                byte ^= (d & 7u) << 4;
                bb[jn] = *(const bf16x8*)(pB + byte);
            }
#pragma unroll
            for (int i = 0; i < 2; ++i)
#pragma unroll
                for (int jn = 0; jn < 2; ++jn)
                    acc[i][jn] = __builtin_amdgcn_mfma_f32_16x16x32_bf16(a[i], bb[jn], acc[i][jn], 0, 0, 0);
        }
        __builtin_amdgcn_s_barrier();

#pragma unroll
        for (int j = 0; j < 4; ++j) aA[j] = nA[j];
    }

    // epilogue: rs[n]*acc, relu, store
#pragma unroll
    for (int i = 0; i < 2; ++i) {
#pragma unroll
        for (int r = 0; r < 4; ++r) {
            int rowl = wr * 32 + i * 16 + lh * 4 + r;
            float rsn = sRS[R0 + rowl];
#pragma unroll
            for (int jn = 0; jn < 2; ++jn) {
                int d = wc * 32 + jn * 16 + lr;
                float v = acc[i][jn][r] * rsn;
                out[((size_t)(b * N_ + R0 + rowl)) * D_ + d] = fmaxf(v, 0.f);
            }
        }
    }
}

extern "C" void kernel_launch(void* const* d_in, const int* in_sizes, int n_in,
                              void* d_out, int out_size, void* d_ws, size_t ws_size,
                              hipStream_t stream) {
    const float* inputs = (const float*)d_in[0];   // [B,N,F]
    const float* adj    = (const float*)d_in[1];   // [B,N,N]
    const float* Wk     = (const float*)d_in[2];   // [F,D]
    const float* Wb     = (const float*)d_in[3];   // [D]
    float* out = (float*)d_out;

    float* rs = (float*)d_ws;                                          // 64 KB
    unsigned short* gt = (unsigned short*)((char*)d_ws + 65536);       // 4 MB
    unsigned int* flags = (unsigned int*)((char*)d_ws + 65536 + (size_t)B_ * D_ * N_ * 2);

    hipMemsetAsync(flags, 0, 1024, stream);

    void* args[] = {(void*)&adj, (void*)&inputs, (void*)&Wk, (void*)&Wb,
                    (void*)&rs, (void*)&gt, (void*)&flags, (void*)&out};
    hipLaunchCooperativeKernel((void*)k_fused, dim3(256), dim3(512), args, 0, stream);
}

// Round 8
// 58.233 us; speedup vs baseline: 1.6125x; 1.6125x over previous
//
#include <hip/hip_runtime.h>
#include <hip/hip_bf16.h>
#include <stdint.h>

#define B_ 8
#define N_ 2048
#define F_ 128
#define D_ 128

typedef short bf16x8 __attribute__((ext_vector_type(8)));
typedef float f32x4 __attribute__((ext_vector_type(4)));

__device__ __forceinline__ unsigned short f2bf(float f) {
    unsigned u = __float_as_uint(f);
    u += 0x7fffu + ((u >> 16) & 1u);
    return (unsigned short)(u >> 16);
}

// ---------------- Kernel 1: rowsums -> rs, adj -> bf16 copy, + W transpose tail ----------------
// blocks 0..4095: 4 rows each (wave per row): s = rowsum; adjbf[row] = bf16(adj[row]).
// blocks 4096..4103: transpose W[f][d] fp32 -> Wt[d][f] bf16.
__global__ __launch_bounds__(256) void k_degwt(const float* __restrict__ adj,
                                               const float* __restrict__ W,
                                               float* __restrict__ rs,
                                               unsigned short* __restrict__ adjbf,
                                               unsigned short* __restrict__ Wt) {
    if (blockIdx.x < 4096) {
        const int wave = threadIdx.x >> 6, lane = threadIdx.x & 63;
        const int row = blockIdx.x * 4 + wave;          // 0..B_*N_-1
        const float4* p = (const float4*)(adj + (size_t)row * N_);
        unsigned short* q = adjbf + (size_t)row * N_;
        float s = 0.f;
#pragma unroll
        for (int j = 0; j < 8; ++j) {
            float4 v = p[j * 64 + lane];
            s += (v.x + v.y) + (v.z + v.w);
            unsigned u0, u1;
            asm("v_cvt_pk_bf16_f32 %0, %1, %2" : "=v"(u0) : "v"(v.x), "v"(v.y));
            asm("v_cvt_pk_bf16_f32 %0, %1, %2" : "=v"(u1) : "v"(v.z), "v"(v.w));
            uint2 pk; pk.x = u0; pk.y = u1;
            *(uint2*)(q + j * 256 + lane * 4) = pk;
        }
#pragma unroll
        for (int m = 1; m < 64; m <<= 1) s += __shfl_xor(s, m, 64);
        if (lane == 0) rs[row] = (s > 0.f) ? (1.0f / sqrtf(s)) : 0.f;
    } else {
        int c = (blockIdx.x - 4096) * 256 + threadIdx.x;
        int d = c >> 4, f0 = (c & 15) * 8;
        union { bf16x8 v; unsigned short u[8]; } pk;
#pragma unroll
        for (int e = 0; e < 8; ++e) pk.u[e] = f2bf(W[(size_t)(f0 + e) * D_ + d]);
        *(bf16x8*)(Wt + (size_t)d * F_ + f0) = pk.v;
    }
}

// ---------------- Kernel 2: gt[b][d][m] = rs[m]*(X@W + bias)^T, bf16 (pre-scaled) ----------------
__global__ __launch_bounds__(256) void k_feat(const float* __restrict__ x,
                                              const unsigned short* __restrict__ Wt,
                                              const float* __restrict__ bias,
                                              const float* __restrict__ rs,
                                              unsigned short* __restrict__ gt) {
    __shared__ __align__(16) unsigned char sX[64 * 128 * 2];
    __shared__ __align__(16) unsigned char sW[128 * 128 * 2];
    const int t = threadIdx.x;
    const int R0 = blockIdx.x * 64;

#pragma unroll
    for (int j = 0; j < 8; ++j) {
        int c = j * 256 + t;
        unsigned L = (unsigned)c * 16u;
        unsigned lg = L ^ (((L >> 8) & 7u) << 4);
        const unsigned char* src = (const unsigned char*)Wt + lg;
        __builtin_amdgcn_global_load_lds(
            (const __attribute__((address_space(1))) void*)src,
            (__attribute__((address_space(3))) void*)(sW + L), 16, 0, 0);
    }
#pragma unroll
    for (int j = 0; j < 4; ++j) {
        int c = j * 256 + t;
        int row = c >> 4, sub = c & 15;
        const float4* src = (const float4*)(x + (size_t)(R0 + row) * F_ + sub * 8);
        float4 v0 = src[0], v1 = src[1];
        union { bf16x8 v; unsigned short u[8]; } pk;
        pk.u[0] = f2bf(v0.x); pk.u[1] = f2bf(v0.y); pk.u[2] = f2bf(v0.z); pk.u[3] = f2bf(v0.w);
        pk.u[4] = f2bf(v1.x); pk.u[5] = f2bf(v1.y); pk.u[6] = f2bf(v1.z); pk.u[7] = f2bf(v1.w);
        unsigned byte = (unsigned)(row * 256 + sub * 16);
        byte ^= ((byte >> 8) & 7u) << 4;
        *(bf16x8*)(sX + byte) = pk.v;
    }
    __syncthreads();

    const int w = t >> 6, l = t & 63, lr = l & 15, lh = l >> 4;
    f32x4 acc[8];
#pragma unroll
    for (int j = 0; j < 8; ++j) acc[j] = (f32x4){0.f, 0.f, 0.f, 0.f};

#pragma unroll
    for (int ks = 0; ks < 4; ++ks) {
        unsigned abyte = (unsigned)((w * 16 + lr) * 256 + lh * 16 + ks * 64);
        abyte ^= ((abyte >> 8) & 7u) << 4;
        bf16x8 a = *(const bf16x8*)(sX + abyte);
#pragma unroll
        for (int j = 0; j < 8; ++j) {
            unsigned bbyte = (unsigned)((j * 16 + lr) * 256 + lh * 16 + ks * 64);
            bbyte ^= ((bbyte >> 8) & 7u) << 4;
            bf16x8 bb = *(const bf16x8*)(sW + bbyte);
            acc[j] = __builtin_amdgcn_mfma_f32_16x16x32_bf16(a, bb, acc[j], 0, 0, 0);
        }
    }

    const int m0 = R0 + w * 16 + lh * 4;
    float4 r4 = *(const float4*)(rs + m0);
    float rr[4] = {r4.x, r4.y, r4.z, r4.w};
#pragma unroll
    for (int j = 0; j < 8; ++j) {
        int d = j * 16 + lr;
        float bv = bias[d];
#pragma unroll
        for (int r = 0; r < 4; ++r) {
            int m = m0 + r;
            int b = m >> 11, n = m & (N_ - 1);
            gt[((size_t)b * D_ + d) * N_ + n] = f2bf((acc[j][r] + bv) * rr[r]);
        }
    }
}

// ---------------- Kernel 3: out = relu(rs[n] * (adjbf @ gt^T)) ----------------
// 512 blocks (2/CU), 512 thr. BM=32 BN=128 BK=128. Pure-DMA staging (A bf16 + B bf16),
// 5 VMEM/stage, counted vmcnt(5). 8 waves = 2 Kg x 4 Cg (32x32 tiles, K-split + merge).
__global__ __launch_bounds__(512) void k_gcn(const unsigned short* __restrict__ adjbf,
                                             const unsigned short* __restrict__ gt,
                                             const float* __restrict__ rs,
                                             float* __restrict__ out) {
    __shared__ __align__(16) unsigned char sA[2][32 * 256];    // 2 x 8 KB
    __shared__ __align__(16) unsigned char sB[2][128 * 256];   // 2 x 32 KB  (80 KB total)

    unsigned bid = blockIdx.x;
    unsigned wg = (bid & 7u) * 64u + (bid >> 3);
    const int b = (int)(wg >> 6);
    const int R0 = (int)(wg & 63u) * 32;

    const unsigned short* adjB = adjbf + (size_t)(b * N_ + R0) * N_;
    const unsigned short* gtB = gt + (size_t)b * D_ * N_;
    const float* rsB = rs + (size_t)b * N_;

    const int t = threadIdx.x;
    const int w = t >> 6, l = t & 63, lr = l & 15, lh = l >> 4;
    const int kg = w >> 2, cg = w & 3;

    // A geometry: 1 chunk/thread. Linear LDS dest, inverse-swizzled global source.
    const unsigned aL = (unsigned)t * 16u;
    const unsigned aRow = aL >> 8;                      // 0..31
    const unsigned aWi = (aL & 255u) ^ ((aRow & 7u) << 4);
    const unsigned short* aSrcBase = adjB + (size_t)aRow * N_ + (aWi >> 1);

    // B geometry: 4 chunks/thread.
    const unsigned short* bSrc[4];
    unsigned bL[4];
#pragma unroll
    for (int i = 0; i < 4; ++i) {
        unsigned c = (unsigned)(i * 512 + t);
        unsigned L = c * 16u;
        unsigned lg = L ^ (((L >> 8) & 7u) << 4);
        bL[i] = L;
        bSrc[i] = gtB + (size_t)(lg >> 8) * N_ + ((lg & 255u) >> 1);
    }

    auto stage = [&](int buf, int k0) {
        unsigned char* pB = sB[buf];
#pragma unroll
        for (int i = 0; i < 4; ++i) {
            __builtin_amdgcn_global_load_lds(
                (const __attribute__((address_space(1))) void*)(bSrc[i] + k0),
                (__attribute__((address_space(3))) void*)(pB + bL[i]), 16, 0, 0);
        }
        __builtin_amdgcn_global_load_lds(
            (const __attribute__((address_space(1))) void*)(aSrcBase + k0),
            (__attribute__((address_space(3))) void*)(sA[buf] + aL), 16, 0, 0);
    };

    f32x4 acc[2][2];
#pragma unroll
    for (int i = 0; i < 2; ++i)
#pragma unroll
        for (int jn = 0; jn < 2; ++jn) acc[i][jn] = (f32x4){0.f, 0.f, 0.f, 0.f};

    stage(0, 0);

    const int NITER = N_ / 128;  // 16
    for (int it = 0; it < NITER; ++it) {
        const int cur = it & 1;
        if (it + 1 < NITER) {
            stage(cur ^ 1, (it + 1) * 128);
            asm volatile("s_waitcnt vmcnt(5)" ::: "memory");   // stage(it) landed
        } else {
            asm volatile("s_waitcnt vmcnt(0)" ::: "memory");
        }
        __builtin_amdgcn_sched_barrier(0);
        __builtin_amdgcn_s_barrier();

        const unsigned char* pA = sA[cur];
        const unsigned char* pB = sB[cur];
#pragma unroll
        for (int kk2 = 0; kk2 < 2; ++kk2) {
            const int kk = kg * 2 + kk2;
            bf16x8 a[2], bb[2];
#pragma unroll
            for (int i = 0; i < 2; ++i) {
                unsigned row = (unsigned)(i * 16 + lr);
                unsigned byte = row * 256 + (unsigned)(lh * 16 + kk * 64);
                byte ^= (row & 7u) << 4;
                a[i] = *(const bf16x8*)(pA + byte);
            }
#pragma unroll
            for (int jn = 0; jn < 2; ++jn) {
                unsigned d = (unsigned)(cg * 32 + jn * 16 + lr);
                unsigned byte = d * 256 + (unsigned)(lh * 16 + kk * 64);
                byte ^= (d & 7u) << 4;
                bb[jn] = *(const bf16x8*)(pB + byte);
            }
#pragma unroll
            for (int i = 0; i < 2; ++i)
#pragma unroll
                for (int jn = 0; jn < 2; ++jn)
                    acc[i][jn] = __builtin_amdgcn_mfma_f32_16x16x32_bf16(a[i], bb[jn], acc[i][jn], 0, 0, 0);
        }
        __builtin_amdgcn_s_barrier();
    }

    // merge the two K-groups' partials via (dead) sA, then store
    float* sO = (float*)sA;   // 32 x 128 f32 = 16 KB
    if (kg == 1) {
#pragma unroll
        for (int i = 0; i < 2; ++i)
#pragma unroll
            for (int jn = 0; jn < 2; ++jn)
#pragma unroll
                for (int r = 0; r < 4; ++r) {
                    int rowl = i * 16 + lh * 4 + r;
                    int d = cg * 32 + jn * 16 + lr;
                    sO[rowl * 128 + d] = acc[i][jn][r];
                }
    }
    __syncthreads();
    if (kg == 0) {
#pragma unroll
        for (int i = 0; i < 2; ++i) {
            float4 r4 = *(const float4*)(rsB + R0 + i * 16 + lh * 4);
            float rr[4] = {r4.x, r4.y, r4.z, r4.w};
#pragma unroll
            for (int r = 0; r < 4; ++r) {
                int rowl = i * 16 + lh * 4 + r;
#pragma unroll
                for (int jn = 0; jn < 2; ++jn) {
                    int d = cg * 32 + jn * 16 + lr;
                    float v = (acc[i][jn][r] + sO[rowl * 128 + d]) * rr[r];
                    out[((size_t)(b * N_ + R0 + rowl)) * D_ + d] = fmaxf(v, 0.f);
                }
            }
        }
    }
}

extern "C" void kernel_launch(void* const* d_in, const int* in_sizes, int n_in,
                              void* d_out, int out_size, void* d_ws, size_t ws_size,
                              hipStream_t stream) {
    const float* inputs = (const float*)d_in[0];   // [B,N,F]
    const float* adj    = (const float*)d_in[1];   // [B,N,N]
    const float* Wk     = (const float*)d_in[2];   // [F,D]
    const float* Wb     = (const float*)d_in[3];   // [D]
    float* out = (float*)d_out;

    char* ws = (char*)d_ws;
    float* rs           = (float*)ws;                         // 64 KB @ 0
    unsigned short* gt  = (unsigned short*)(ws + (1 << 20));  // 4 MB  @ 1 MB
    unsigned short* Wt  = (unsigned short*)(ws + (6 << 20));  // 32 KB @ 6 MB
    unsigned short* adjbf = (unsigned short*)(ws + (8 << 20)); // 67 MB @ 8 MB

    k_degwt<<<4096 + 8, 256, 0, stream>>>(adj, Wk, rs, adjbf, Wt);
    k_feat <<<(B_ * N_) / 64, 256, 0, stream>>>(inputs, Wt, Wb, rs, gt);
    k_gcn  <<<B_ * (N_ / 32), 512, 0, stream>>>(adjbf, gt, rs, out);
}

// Round 9
// 55.780 us; speedup vs baseline: 1.6834x; 1.0440x over previous
//
#include <hip/hip_runtime.h>
#include <hip/hip_bf16.h>
#include <stdint.h>

#define B_ 8
#define N_ 2048
#define F_ 128
#define D_ 128

typedef short bf16x8 __attribute__((ext_vector_type(8)));
typedef float f32x4 __attribute__((ext_vector_type(4)));

__device__ __forceinline__ unsigned short f2bf(float f) {
    unsigned u = __float_as_uint(f);
    u += 0x7fffu + ((u >> 16) & 1u);
    return (unsigned short)(u >> 16);
}

// ---------------- Kernel 1: degrees -> rsqrt  (+ W transpose in tail blocks) ----------------
__global__ __launch_bounds__(256) void k_degwt(const float* __restrict__ adj,
                                               const float* __restrict__ W,
                                               float* __restrict__ rs,
                                               unsigned short* __restrict__ Wt) {
    if (blockIdx.x < 4096) {
        const int wave = threadIdx.x >> 6, lane = threadIdx.x & 63;
        const int row = blockIdx.x * 4 + wave;          // 0..B_*N_-1
        const float4* p = (const float4*)(adj + (size_t)row * N_);
        float s = 0.f;
#pragma unroll
        for (int j = 0; j < 8; ++j) {
            float4 v = p[j * 64 + lane];
            s += (v.x + v.y) + (v.z + v.w);
        }
#pragma unroll
        for (int m = 1; m < 64; m <<= 1) s += __shfl_xor(s, m, 64);
        if (lane == 0) rs[row] = (s > 0.f) ? (1.0f / sqrtf(s)) : 0.f;
    } else {
        int c = (blockIdx.x - 4096) * 256 + threadIdx.x;
        int d = c >> 4, f0 = (c & 15) * 8;
        union { bf16x8 v; unsigned short u[8]; } pk;
#pragma unroll
        for (int e = 0; e < 8; ++e) pk.u[e] = f2bf(W[(size_t)(f0 + e) * D_ + d]);
        *(bf16x8*)(Wt + (size_t)d * F_ + f0) = pk.v;
    }
}

// ---------------- Kernel 2: gt[b][d][m] = rs[m]*(X@W + bias)^T, bf16 (pre-scaled) ----------------
__global__ __launch_bounds__(256) void k_feat(const float* __restrict__ x,
                                              const unsigned short* __restrict__ Wt,
                                              const float* __restrict__ bias,
                                              const float* __restrict__ rs,
                                              unsigned short* __restrict__ gt) {
    __shared__ __align__(16) unsigned char sX[64 * 128 * 2];
    __shared__ __align__(16) unsigned char sW[128 * 128 * 2];
    const int t = threadIdx.x;
    const int R0 = blockIdx.x * 64;

#pragma unroll
    for (int j = 0; j < 8; ++j) {
        int c = j * 256 + t;
        unsigned L = (unsigned)c * 16u;
        unsigned lg = L ^ (((L >> 8) & 7u) << 4);
        const unsigned char* src = (const unsigned char*)Wt + lg;
        __builtin_amdgcn_global_load_lds(
            (const __attribute__((address_space(1))) void*)src,
            (__attribute__((address_space(3))) void*)(sW + L), 16, 0, 0);
    }
#pragma unroll
    for (int j = 0; j < 4; ++j) {
        int c = j * 256 + t;
        int row = c >> 4, sub = c & 15;
        const float4* src = (const float4*)(x + (size_t)(R0 + row) * F_ + sub * 8);
        float4 v0 = src[0], v1 = src[1];
        union { bf16x8 v; unsigned short u[8]; } pk;
        pk.u[0] = f2bf(v0.x); pk.u[1] = f2bf(v0.y); pk.u[2] = f2bf(v0.z); pk.u[3] = f2bf(v0.w);
        pk.u[4] = f2bf(v1.x); pk.u[5] = f2bf(v1.y); pk.u[6] = f2bf(v1.z); pk.u[7] = f2bf(v1.w);
        unsigned byte = (unsigned)(row * 256 + sub * 16);
        byte ^= ((byte >> 8) & 7u) << 4;
        *(bf16x8*)(sX + byte) = pk.v;
    }
    __syncthreads();

    const int w = t >> 6, l = t & 63, lr = l & 15, lh = l >> 4;
    f32x4 acc[8];
#pragma unroll
    for (int j = 0; j < 8; ++j) acc[j] = (f32x4){0.f, 0.f, 0.f, 0.f};

#pragma unroll
    for (int ks = 0; ks < 4; ++ks) {
        unsigned abyte = (unsigned)((w * 16 + lr) * 256 + lh * 16 + ks * 64);
        abyte ^= ((abyte >> 8) & 7u) << 4;
        bf16x8 a = *(const bf16x8*)(sX + abyte);
#pragma unroll
        for (int j = 0; j < 8; ++j) {
            unsigned bbyte = (unsigned)((j * 16 + lr) * 256 + lh * 16 + ks * 64);
            bbyte ^= ((bbyte >> 8) & 7u) << 4;
            bf16x8 bb = *(const bf16x8*)(sW + bbyte);
            acc[j] = __builtin_amdgcn_mfma_f32_16x16x32_bf16(a, bb, acc[j], 0, 0, 0);
        }
    }

    const int m0 = R0 + w * 16 + lh * 4;
    float4 r4 = *(const float4*)(rs + m0);
    float rr[4] = {r4.x, r4.y, r4.z, r4.w};
#pragma unroll
    for (int j = 0; j < 8; ++j) {
        int d = j * 16 + lr;
        float bv = bias[d];
#pragma unroll
        for (int r = 0; r < 4; ++r) {
            int m = m0 + r;
            int b = m >> 11, n = m & (N_ - 1);
            gt[((size_t)b * D_ + d) * N_ + n] = f2bf((acc[j][r] + bv) * rr[r]);
        }
    }
}

// ---------------- Kernel 3: out = relu(rs[n] * (adj @ gt^T)) ----------------
// 512 blocks (2/CU), 512 thr, BM=32 BN=128 BK=128. 8 waves = 2Kg x 4Cg (32x32, K-split).
// Stage = 4 B-DMA + 2 A-fp32 reg loads = 6 VMEM; vmcnt(6) steady.
// A(it+1) cvt+ds_write happens DURING it's MFMA phase (other buffer) -> off critical path.
__global__ __launch_bounds__(512) void k_gcn(const float* __restrict__ adj,
                                             const unsigned short* __restrict__ gt,
                                             const float* __restrict__ rs,
                                             float* __restrict__ out) {
    __shared__ __align__(16) unsigned char sA[2][32 * 256];    // 2 x 8 KB bf16
    __shared__ __align__(16) unsigned char sB[2][128 * 256];   // 2 x 32 KB bf16 (80 KB total)

    unsigned bid = blockIdx.x;
    unsigned wg = (bid & 7u) * 64u + (bid >> 3);
    const int b = (int)(wg >> 6);
    const int R0 = (int)(wg & 63u) * 32;

    const float* adjB = adj + (size_t)(b * N_ + R0) * N_;
    const unsigned short* gtB = gt + (size_t)b * D_ * N_;
    const float* rsB = rs + (size_t)b * N_;

    const int t = threadIdx.x;
    const int w = t >> 6, l = t & 63, lr = l & 15, lh = l >> 4;
    const int kg = w >> 2, cg = w & 3;

    // A: thread owns row t>>4, 8 fp32 at col (t&15)*8
    const float* aSrc = adjB + (size_t)(t >> 4) * N_ + (t & 15) * 8;
    unsigned aL = (unsigned)((t >> 4) * 256 + (t & 15) * 16);
    aL ^= (((unsigned)(t >> 4) & 7u) << 4);

    // B: 4 chunks/thread, linear LDS dest + inverse-swizzled global src
    const unsigned short* bSrc[4];
    unsigned bL[4];
#pragma unroll
    for (int i = 0; i < 4; ++i) {
        unsigned c = (unsigned)(i * 512 + t);
        unsigned L = c * 16u;
        unsigned lg = L ^ (((L >> 8) & 7u) << 4);
        bL[i] = L;
        bSrc[i] = gtB + (size_t)(lg >> 8) * N_ + ((lg & 255u) >> 1);
    }
    auto issueB = [&](int buf, int k0) {
        unsigned char* pB = sB[buf];
#pragma unroll
        for (int i = 0; i < 4; ++i) {
            __builtin_amdgcn_global_load_lds(
                (const __attribute__((address_space(1))) void*)(bSrc[i] + k0),
                (__attribute__((address_space(3))) void*)(pB + bL[i]), 16, 0, 0);
        }
    };
    auto cvtWrite = [&](int buf, const f32x4& x0, const f32x4& x1) {
        unsigned u0, u1, u2, u3;
        asm("v_cvt_pk_bf16_f32 %0, %1, %2" : "=v"(u0) : "v"(x0[0]), "v"(x0[1]));
        asm("v_cvt_pk_bf16_f32 %0, %1, %2" : "=v"(u1) : "v"(x0[2]), "v"(x0[3]));
        asm("v_cvt_pk_bf16_f32 %0, %1, %2" : "=v"(u2) : "v"(x1[0]), "v"(x1[1]));
        asm("v_cvt_pk_bf16_f32 %0, %1, %2" : "=v"(u3) : "v"(x1[2]), "v"(x1[3]));
        union { unsigned u[4]; bf16x8 v; } pk;
        pk.u[0] = u0; pk.u[1] = u1; pk.u[2] = u2; pk.u[3] = u3;
        *(bf16x8*)(sA[buf] + aL) = pk.v;
    };

    f32x4 acc[2][2];
#pragma unroll
    for (int i = 0; i < 2; ++i)
#pragma unroll
        for (int jn = 0; jn < 2; ++jn) acc[i][jn] = (f32x4){0.f, 0.f, 0.f, 0.f};

    const int NITER = N_ / 128;  // 16

    // prologue: B0 DMA [4], A0 regs [2], A1 regs [2]
    issueB(0, 0);
    f32x4 aCur0 = *(const f32x4*)(aSrc);
    f32x4 aCur1 = *(const f32x4*)(aSrc + 4);
    f32x4 aNxt0 = *(const f32x4*)(aSrc + 128);
    f32x4 aNxt1 = *(const f32x4*)(aSrc + 132);
    asm volatile("s_waitcnt vmcnt(2)" ::: "memory");   // B0 + A0 landed (A1 in flight)
    cvtWrite(0, aCur0, aCur1);                          // sA[0] ready (my slice)
    aCur0 = aNxt0; aCur1 = aNxt1;                       // aCur = A(1) regs (pending vmcnt)
    asm volatile("s_waitcnt lgkmcnt(0)" ::: "memory");

#pragma unroll
    for (int it = 0; it < NITER; ++it) {
        const int cur = it & 1, nxt = cur ^ 1;
        int outst = 0;
        if (it + 1 < NITER) { issueB(nxt, (it + 1) * 128); outst += 4; }
        if (it + 2 < NITER) {
            const float* s = aSrc + (it + 2) * 128;
            aNxt0 = *(const f32x4*)(s);
            aNxt1 = *(const f32x4*)(s + 4);
            outst += 2;
        }
        if (outst == 6)      asm volatile("s_waitcnt vmcnt(6)" ::: "memory");
        else if (outst == 4) asm volatile("s_waitcnt vmcnt(4)" ::: "memory");
        else                 asm volatile("s_waitcnt vmcnt(0)" ::: "memory");
        __builtin_amdgcn_sched_barrier(0);
        __builtin_amdgcn_s_barrier();      // sB[cur] landed everywhere; sA[cur] published (it-1)

        // MFMA over sA[cur]/sB[cur]  (+ convert A(it+1) into sA[nxt], off critical path)
        const unsigned char* pA = sA[cur];
        const unsigned char* pB = sB[cur];
#pragma unroll
        for (int kk2 = 0; kk2 < 2; ++kk2) {
            const int kk = kg * 2 + kk2;
            bf16x8 a[2], bb[2];
#pragma unroll
            for (int i = 0; i < 2; ++i) {
                unsigned row = (unsigned)(i * 16 + lr);
                unsigned byte = row * 256 + (unsigned)(lh * 16 + kk * 64);
                byte ^= (row & 7u) << 4;
                a[i] = *(const bf16x8*)(pA + byte);
            }
#pragma unroll
            for (int jn = 0; jn < 2; ++jn) {
                unsigned d = (unsigned)(cg * 32 + jn * 16 + lr);
                unsigned byte = d * 256 + (unsigned)(lh * 16 + kk * 64);
                byte ^= (d & 7u) << 4;
                bb[jn] = *(const bf16x8*)(pB + byte);
            }
#pragma unroll
            for (int i = 0; i < 2; ++i)
#pragma unroll
                for (int jn = 0; jn < 2; ++jn)
                    acc[i][jn] = __builtin_amdgcn_mfma_f32_16x16x32_bf16(a[i], bb[jn], acc[i][jn], 0, 0, 0);
        }
        if (it + 1 < NITER) {
            cvtWrite(nxt, aCur0, aCur1);   // A(it+1) -> sA[nxt]
            aCur0 = aNxt0; aCur1 = aNxt1;  // roll regs: aCur = A(it+2)
        }
        asm volatile("s_waitcnt lgkmcnt(0)" ::: "memory");
        __builtin_amdgcn_sched_barrier(0);
        __builtin_amdgcn_s_barrier();
    }

    // merge the two K-groups' partials via (dead) sA, then store
    float* sO = (float*)sA;   // 32 x 128 f32 = 16 KB
    if (kg == 1) {
#pragma unroll
        for (int i = 0; i < 2; ++i)
#pragma unroll
            for (int jn = 0; jn < 2; ++jn)
#pragma unroll
                for (int r = 0; r < 4; ++r) {
                    int rowl = i * 16 + lh * 4 + r;
                    int d = cg * 32 + jn * 16 + lr;
                    sO[rowl * 128 + d] = acc[i][jn][r];
                }
    }
    __syncthreads();
    if (kg == 0) {
#pragma unroll
        for (int i = 0; i < 2; ++i) {
            float4 r4 = *(const float4*)(rsB + R0 + i * 16 + lh * 4);
            float rr[4] = {r4.x, r4.y, r4.z, r4.w};
#pragma unroll
            for (int r = 0; r < 4; ++r) {
                int rowl = i * 16 + lh * 4 + r;
#pragma unroll
                for (int jn = 0; jn < 2; ++jn) {
                    int d = cg * 32 + jn * 16 + lr;
                    float v = (acc[i][jn][r] + sO[rowl * 128 + d]) * rr[r];
                    out[((size_t)(b * N_ + R0 + rowl)) * D_ + d] = fmaxf(v, 0.f);
                }
            }
        }
    }
}

extern "C" void kernel_launch(void* const* d_in, const int* in_sizes, int n_in,
                              void* d_out, int out_size, void* d_ws, size_t ws_size,
                              hipStream_t stream) {
    const float* inputs = (const float*)d_in[0];   // [B,N,F]
    const float* adj    = (const float*)d_in[1];   // [B,N,N]
    const float* Wk     = (const float*)d_in[2];   // [F,D]
    const float* Wb     = (const float*)d_in[3];   // [D]
    float* out = (float*)d_out;

    char* ws = (char*)d_ws;
    float* rs          = (float*)ws;                          // 64 KB @ 0
    unsigned short* gt = (unsigned short*)(ws + (1 << 20));   // 4 MB  @ 1 MB
    unsigned short* Wt = (unsigned short*)(ws + (6 << 20));   // 32 KB @ 6 MB

    k_degwt<<<4096 + 8, 256, 0, stream>>>(adj, Wk, rs, Wt);
    k_feat <<<(B_ * N_) / 64, 256, 0, stream>>>(inputs, Wt, Wb, rs, gt);
    k_gcn  <<<B_ * (N_ / 32), 512, 0, stream>>>(adj, gt, rs, out);
}